// Round 16
// baseline (1627.196 us; speedup 1.0000x reference)
//
#include <hip/hip_runtime.h>
#include <hip/hip_bf16.h>
#include <hip/hip_fp16.h>

#define E_ 16
#define T_ 128

typedef _Float16 h2_t __attribute__((ext_vector_type(2)));
typedef _Float16 half4_t __attribute__((ext_vector_type(4)));
typedef _Float16 half8_t __attribute__((ext_vector_type(8)));
typedef float f32x4 __attribute__((ext_vector_type(4)));

__device__ __forceinline__ float fdot2u(uint32_t w, uint32_t h, float acc) {
#if __has_builtin(__builtin_amdgcn_fdot2)
  return __builtin_amdgcn_fdot2(__builtin_bit_cast(h2_t, w),
                                __builtin_bit_cast(h2_t, h), acc, false);
#else
  h2_t wv = __builtin_bit_cast(h2_t, w), hv = __builtin_bit_cast(h2_t, h);
  return acc + (float)wv.x * (float)hv.x + (float)wv.y * (float)hv.y;
#endif
}

__device__ __forceinline__ uint32_t rdlane(uint32_t v, int l) {
  return (uint32_t)__builtin_amdgcn_readlane((int)v, l);
}

__device__ __forceinline__ uint32_t packh2(float a, float b) {
  h2_t p; p.x = (_Float16)a; p.y = (_Float16)b;
  return __builtin_bit_cast(uint32_t, p);
}

__device__ __forceinline__ float apply_act(float v, int act) {
  if (act == 1) return tanhf(v);
  if (act == 2) { // jax.nn.gelu approximate=True
    const float c = 0.7978845608028654f;
    return 0.5f * v * (1.0f + tanhf(c * (v + 0.044715f * v * v * v)));
  }
  return v;
}

// ---- MFMA GEMM (unchanged from round 12, verified passing) ----
template<int NT>
__global__ void __launch_bounds__(256) gemm_mfma(
    const float* __restrict__ A, const float* __restrict__ W,
    const float* __restrict__ bias, float* __restrict__ C, float* __restrict__ part,
    int N, int K, int lda, int ldc,
    long sAe, long sWe, long sBe, long sCe,
    int S, int act)
{
  int n0 = blockIdx.x * (32 * NT);
  int e  = blockIdx.y;
  int s  = blockIdx.z;
  const float* Ae = A + (long)e * sAe;
  const float* We = W + (long)e * sWe;
  int kper = K / S;
  int kb = s * kper, ke2 = kb + kper;

  __shared__ _Float16 As[128 * 40];   // 10,240 B

  int tid  = threadIdx.x;
  int lane = tid & 63;
  int w    = tid >> 6;
  int wm   = (w >> 1) * 64;
  int wn   = (w & 1) * (16 * NT);
  int l16  = lane & 15;
  int lk   = lane >> 4;

  f32x4 acc[4][NT];
  #pragma unroll
  for (int i = 0; i < 4; ++i)
    #pragma unroll
    for (int j = 0; j < NT; ++j)
      acc[i][j] = (f32x4){0.f, 0.f, 0.f, 0.f};

  for (int k0 = kb; k0 < ke2; k0 += 32) {
    __syncthreads();
    #pragma unroll
    for (int i = 0; i < 4; ++i) {
      int idx = tid + 256 * i;
      int row = idx >> 3, k4 = idx & 7;
      float4 a4 = *(const float4*)(Ae + (long)row * lda + k0 + k4 * 4);
      half4_t hv;
      hv.x = (_Float16)a4.x; hv.y = (_Float16)a4.y;
      hv.z = (_Float16)a4.z; hv.w = (_Float16)a4.w;
      *(half4_t*)(&As[row * 40 + k4 * 4]) = hv;
    }
    __syncthreads();
    #pragma unroll
    for (int nt = 0; nt < NT; ++nt) {
      int ncol = n0 + wn + nt * 16 + l16;
      const float* Wc = We + (long)(k0 + lk * 8) * N + ncol;
      half8_t b;
      #pragma unroll
      for (int j = 0; j < 8; ++j) b[j] = (_Float16)Wc[(long)j * N];
      #pragma unroll
      for (int mt = 0; mt < 4; ++mt) {
        half8_t a = *(const half8_t*)(&As[(wm + mt * 16 + l16) * 40 + lk * 8]);
        acc[mt][nt] = __builtin_amdgcn_mfma_f32_16x16x32_f16(a, b, acc[mt][nt], 0, 0, 0);
      }
    }
  }

  if (S == 1) {
    #pragma unroll
    for (int mt = 0; mt < 4; ++mt)
      #pragma unroll
      for (int nt = 0; nt < NT; ++nt) {
        int col = n0 + wn + nt * 16 + l16;
        float bv = bias[(long)e * sBe + col];
        #pragma unroll
        for (int r = 0; r < 4; ++r) {
          int row = wm + mt * 16 + lk * 4 + r;
          C[(long)e * sCe + (long)row * ldc + col] = apply_act(acc[mt][nt][r] + bv, act);
        }
      }
  } else {
    float* pp = part + ((long)(s * gridDim.y + e) * 128) * N;
    #pragma unroll
    for (int mt = 0; mt < 4; ++mt)
      #pragma unroll
      for (int nt = 0; nt < NT; ++nt) {
        int col = n0 + wn + nt * 16 + l16;
        #pragma unroll
        for (int r = 0; r < 4; ++r) {
          int row = wm + mt * 16 + lk * 4 + r;
          pp[(long)row * N + col] = acc[mt][nt][r];
        }
      }
  }
}

// reduce split-K partials + bias + act -> C (unchanged)
__global__ void __launch_bounds__(256) reduce_ep(
    const float* __restrict__ part, const float* __restrict__ bias, float* __restrict__ C,
    int S, int N, int ldc, long sBe, long sCe, int act, int total, int Eb)
{
  int idx = blockIdx.x * 256 + threadIdx.x;
  if (idx >= total) return;
  int n = idx % N;
  int r = (idx / N) & 127;
  int e = idx / (N * 128);
  long sstride = (long)Eb * 128 * N;
  float v = 0.f;
  for (int s = 0; s < S; ++s) v += part[s * sstride + ((long)e * 128 + r) * N + n];
  v = apply_act(v + bias[(long)e * sBe + n], act);
  C[(long)e * sCe + (long)r * ldc + n] = v;
}

// ---- sequential RNN layer: h[t] = tanh(P[t] + h[t-1] @ Wh) ----
// BLOCK=512 VALU/dot2 engine. R15 post-mortem: at block=1024 the 128-total-
// reg/thread wall makes every fragment scheme spill. At block=512 the caps
// are friendly (both HW-verified): arch VGPR cap = 65536/512 = 128 and IS
// honored (R3 counter VGPR_Count=128); total budget at 2 waves/SIMD = 256
// regs/thread, so up to 128 AGPRs are also legal (R13 proved asm "a" pins
// allocate above the arch cap).
// ONE workgroup per encoder, 512 threads; thread owns ONE column (tid) over
// the FULL K=512 -> no cross-wave reduction, 2 barriers/step. 256 weight
// pairs/thread (pair q = k 2q,2q+1), partitioned:
//   q in [0,96)    : 96 uints in arch VGPRs     (L-groups 0..23)
//   q in [96,192)  : 96 uints in AGPRs          (L-groups 24..47, asm-pinned)
//   q in [192,256) : 64 uints in LDS, 131072 B  (L-groups 48..63)
// Audit: arch 96+~26 = 122 <= 128; AGPR 96 <= 128; zero spill w/ margin.
// h broadcast: hbuf (512 fp16) in LDS; each lane ONE uint4 read (pairs
// 4*lane..4*lane+3), then rdlane(hr.comp, L) -> SGPR operand of dot2.
// Step: ~635 VALU ops x 2 cyc x 2 waves/SIMD ~= 2550 cyc ~= 1.06 us
// -> ~140 us/layer (R12: 295; R15 MFMA: 418).
#define RW_NVL 24   // arch-VGPR L-groups  (q 0..95)
#define RW_AL0 24   // first AGPR L-group  (q 96..191, 12 macro-groups of 8)
#define RW_LL0 48   // first LDS L-group   (q 192..255, 16 uint4 groups)

#define AG_DECL(j) uint32_t ag##j##_0, ag##j##_1, ag##j##_2, ag##j##_3, \
                            ag##j##_4, ag##j##_5, ag##j##_6, ag##j##_7
#define AG_W(x, var) asm volatile("v_accvgpr_write_b32 %0, %1" : "=a"(var) : "v"(x))
#define AG_R(var, tmp) asm volatile("v_accvgpr_read_b32 %0, %1" : "=v"(tmp) : "a"(var))
#define AG_PACKQ(q, var) do { \
    uint32_t u_ = packh2(W[(long)(2 * (q)) * 512], W[(long)(2 * (q) + 1) * 512]); \
    AG_W(u_, var); } while (0)
#define AG_PACK8(j, Lb) do { \
    AG_PACKQ(4 * (Lb) + 0, ag##j##_0); AG_PACKQ(4 * (Lb) + 1, ag##j##_1); \
    AG_PACKQ(4 * (Lb) + 2, ag##j##_2); AG_PACKQ(4 * (Lb) + 3, ag##j##_3); \
    AG_PACKQ(4 * (Lb) + 4, ag##j##_4); AG_PACKQ(4 * (Lb) + 5, ag##j##_5); \
    AG_PACKQ(4 * (Lb) + 6, ag##j##_6); AG_PACKQ(4 * (Lb) + 7, ag##j##_7); } while (0)
#define AG_DOT8(j, Lb) do { \
    uint32_t t_; \
    uint32_t h0_ = rdlane(hr.x, (Lb)), h1_ = rdlane(hr.y, (Lb)); \
    uint32_t h2_ = rdlane(hr.z, (Lb)), h3_ = rdlane(hr.w, (Lb)); \
    AG_R(ag##j##_0, t_); a0 = fdot2u(t_, h0_, a0); \
    AG_R(ag##j##_1, t_); a1 = fdot2u(t_, h1_, a1); \
    AG_R(ag##j##_2, t_); a2 = fdot2u(t_, h2_, a2); \
    AG_R(ag##j##_3, t_); a3 = fdot2u(t_, h3_, a3); \
    h0_ = rdlane(hr.x, (Lb) + 1); h1_ = rdlane(hr.y, (Lb) + 1); \
    h2_ = rdlane(hr.z, (Lb) + 1); h3_ = rdlane(hr.w, (Lb) + 1); \
    AG_R(ag##j##_4, t_); a0 = fdot2u(t_, h0_, a0); \
    AG_R(ag##j##_5, t_); a1 = fdot2u(t_, h1_, a1); \
    AG_R(ag##j##_6, t_); a2 = fdot2u(t_, h2_, a2); \
    AG_R(ag##j##_7, t_); a3 = fdot2u(t_, h3_, a3); } while (0)

__global__ void
__attribute__((amdgpu_flat_work_group_size(512, 512)))
__attribute__((amdgpu_waves_per_eu(2, 2)))
rnn_seq(
    const float* __restrict__ P,     // [T][E][512], pre-activation incl. bias
    const float* __restrict__ Wh,    // + e*sWe : [512][512]
    float* __restrict__ H,           // (t*E+e)*1536 + col (layer offset by caller)
    long sWe)
{
  __shared__ uint32_t lw[16 * 512 * 4];   // 131,072 B  [g][tid][4]
  __shared__ uint32_t hbuf[256];          //   1,024 B  (512 fp16)

  int tid  = threadIdx.x;            // this thread's column
  int lane = tid & 63;
  int e    = blockIdx.x;

  const float* W = Wh + (long)e * sWe + tid;   // element (k, tid) at W[k*512]

  AG_DECL(0); AG_DECL(1); AG_DECL(2);  AG_DECL(3);  AG_DECL(4);  AG_DECL(5);
  AG_DECL(6); AG_DECL(7); AG_DECL(8);  AG_DECL(9);  AG_DECL(10); AG_DECL(11);

  // arch-VGPR weights: pair q = 4L+j, L in [0, RW_NVL)
  uint32_t wv[RW_NVL * 4];
  #pragma unroll
  for (int q = 0; q < RW_NVL * 4; ++q)
    wv[q] = packh2(W[(long)(2 * q) * 512], W[(long)(2 * q + 1) * 512]);
  // AGPR weights: L in [24, 48)
  AG_PACK8(0,  RW_AL0 + 0);  AG_PACK8(1,  RW_AL0 + 2);
  AG_PACK8(2,  RW_AL0 + 4);  AG_PACK8(3,  RW_AL0 + 6);
  AG_PACK8(4,  RW_AL0 + 8);  AG_PACK8(5,  RW_AL0 + 10);
  AG_PACK8(6,  RW_AL0 + 12); AG_PACK8(7,  RW_AL0 + 14);
  AG_PACK8(8,  RW_AL0 + 16); AG_PACK8(9,  RW_AL0 + 18);
  AG_PACK8(10, RW_AL0 + 20); AG_PACK8(11, RW_AL0 + 22);
  // LDS weights: L in [48, 64), group g covers q = 4*(48+g)..+3
  for (int g = 0; g < 16; ++g) {
    int q0 = 4 * (RW_LL0 + g);
    uint4 v;
    v.x = packh2(W[(long)(2 * (q0 + 0)) * 512], W[(long)(2 * (q0 + 0) + 1) * 512]);
    v.y = packh2(W[(long)(2 * (q0 + 1)) * 512], W[(long)(2 * (q0 + 1) + 1) * 512]);
    v.z = packh2(W[(long)(2 * (q0 + 2)) * 512], W[(long)(2 * (q0 + 2) + 1) * 512]);
    v.w = packh2(W[(long)(2 * (q0 + 3)) * 512], W[(long)(2 * (q0 + 3) + 1) * 512]);
    *(uint4*)(lw + ((long)g * 512 + tid) * 4) = v;
  }
  if (tid < 256) hbuf[tid] = 0;      // h(-1) = 0
  __syncthreads();

  for (int t = 0; t < T_; ++t) {
    float p = P[((long)t * E_ + e) * 512 + tid];
    uint4 hr = *(const uint4*)(hbuf + lane * 4);   // pairs 4*lane .. 4*lane+3
    float a0 = 0.f, a1 = 0.f, a2 = 0.f, a3 = 0.f;
    // arch-VGPR portion: L 0..23
    #pragma unroll
    for (int L = 0; L < RW_NVL; ++L) {
      a0 = fdot2u(wv[4 * L + 0], rdlane(hr.x, L), a0);
      a1 = fdot2u(wv[4 * L + 1], rdlane(hr.y, L), a1);
      a2 = fdot2u(wv[4 * L + 2], rdlane(hr.z, L), a2);
      a3 = fdot2u(wv[4 * L + 3], rdlane(hr.w, L), a3);
    }
    // AGPR portion: L 24..47
    AG_DOT8(0,  RW_AL0 + 0);  AG_DOT8(1,  RW_AL0 + 2);
    AG_DOT8(2,  RW_AL0 + 4);  AG_DOT8(3,  RW_AL0 + 6);
    AG_DOT8(4,  RW_AL0 + 8);  AG_DOT8(5,  RW_AL0 + 10);
    AG_DOT8(6,  RW_AL0 + 12); AG_DOT8(7,  RW_AL0 + 14);
    AG_DOT8(8,  RW_AL0 + 16); AG_DOT8(9,  RW_AL0 + 18);
    AG_DOT8(10, RW_AL0 + 20); AG_DOT8(11, RW_AL0 + 22);
    // LDS portion: L 48..63
    #pragma unroll
    for (int g = 0; g < 16; ++g) {
      uint4 v = *(const uint4*)(lw + (g * 512 + tid) * 4);
      int L = RW_LL0 + g;
      a0 = fdot2u(v.x, rdlane(hr.x, L), a0);
      a1 = fdot2u(v.y, rdlane(hr.y, L), a1);
      a2 = fdot2u(v.z, rdlane(hr.z, L), a2);
      a3 = fdot2u(v.w, rdlane(hr.w, L), a3);
    }
    __syncthreads();                 // all hbuf reads complete before rewrite
    float v0 = tanhf((a0 + a1) + (a2 + a3) + p);
    H[((long)t * E_ + e) * 1536 + tid] = v0;
    ((_Float16*)hbuf)[tid] = (_Float16)v0;
    __syncthreads();                 // new h visible for next step
  }
}

extern "C" void kernel_launch(void* const* d_in, const int* in_sizes, int n_in,
                              void* d_out, int out_size, void* d_ws, size_t ws_size,
                              hipStream_t stream)
{
  const float* x      = (const float*)d_in[0];
  const float* W_in0  = (const float*)d_in[1];
  const float* Wh0    = (const float*)d_in[2];
  const float* b0     = (const float*)d_in[3];
  const float* W_inr  = (const float*)d_in[4];
  const float* Wh_r   = (const float*)d_in[5];
  const float* b_r    = (const float*)d_in[6];
  const float* W_ff1  = (const float*)d_in[7];
  const float* b_ff1  = (const float*)d_in[8];
  const float* W_ff2  = (const float*)d_in[9];
  const float* b_ff2  = (const float*)d_in[10];
  const float* W_d0   = (const float*)d_in[11];
  const float* b_d0   = (const float*)d_in[12];
  const float* W_dmid = (const float*)d_in[13];
  const float* b_dmid = (const float*)d_in[14];
  const float* W_dout = (const float*)d_in[15];
  const float* b_dout = (const float*)d_in[16];
  float* ws = (float*)d_ws;

  // workspace layout (floats)
  float* h    = ws;                    // [T][E][3][512]  3,145,728
  float* P    = ws + 3145728;          // [T][E][512]     1,048,576
  float* FF   = ws + 4194304;          // [T][E][2048]    4,194,304
  float* ENC  = ws + 8388608;          // [T][E*512]      1,048,576
  float* Z0   = ws + 9437184;          // [128][2048]       262,144
  float* Z1   = ws + 9699328;
  float* Z2   = ws + 9961472;
  float* PART = ws + 10223616;         // split-K partials 2,097,152

  (void)in_sizes; (void)n_in; (void)out_size; (void)ws_size;

  dim3 blk(256);

  // P = x @ W_in0 + b0
  gemm_mfma<2><<<dim3(8,16,1), blk, 0, stream>>>(x, W_in0, b0, P, PART,
      512, 32, 32, 8192, 0L, 16384L, 512L, 512L, 1, 0);
  // layer 0 recurrence
  rnn_seq<<<dim3(16), dim3(512), 0, stream>>>(P, Wh0, h, 262144L);
  // P = h0 @ W_in_rest[:,0] + b_rest[:,0]
  gemm_mfma<1><<<dim3(16,16,1), blk, 0, stream>>>(h, W_inr, b_r, P, PART,
      512, 512, 24576, 8192, 1536L, 524288L, 1024L, 512L, 1, 0);
  rnn_seq<<<dim3(16), dim3(512), 0, stream>>>(P, Wh_r, h + 512, 524288L);
  // P = h1 @ W_in_rest[:,1] + b_rest[:,1]
  gemm_mfma<1><<<dim3(16,16,1), blk, 0, stream>>>(h + 512, W_inr + 262144, b_r + 512, P, PART,
      512, 512, 24576, 8192, 1536L, 524288L, 1024L, 512L, 1, 0);
  rnn_seq<<<dim3(16), dim3(512), 0, stream>>>(P, Wh_r + 262144, h + 1024, 524288L);
  // FF1: gelu(cat @ W_ff1 + b_ff1) — 512 blocks = 2 WG/CU
  gemm_mfma<2><<<dim3(32,16,1), blk, 0, stream>>>(h, W_ff1, b_ff1, FF, PART,
      2048, 1536, 24576, 32768, 1536L, 3145728L, 2048L, 2048L, 1, 2);
  // FF2 (split-2): ENC = FF @ W_ff2 + b_ff2 — 512 blocks
  gemm_mfma<1><<<dim3(16,16,2), blk, 0, stream>>>(FF, W_ff2, b_ff2, ENC, PART,
      512, 2048, 32768, 8192, 2048L, 1048576L, 512L, 512L, 2, 0);
  reduce_ep<<<dim3(4096), blk, 0, stream>>>(PART, b_ff2, ENC,
      2, 512, 8192, 512L, 512L, 0, 16*128*512, 16);
  // decoder: Z0 = tanh(ENC @ W_d0 + b_d0)   (split-8)
  gemm_mfma<2><<<dim3(32,1,8), blk, 0, stream>>>(ENC, W_d0, b_d0, Z0, PART,
      2048, 8192, 8192, 2048, 0L, 0L, 0L, 0L, 8, 0);
  reduce_ep<<<dim3(1024), blk, 0, stream>>>(PART, b_d0, Z0,
      8, 2048, 2048, 0L, 0L, 1, 128*2048, 1);
  // Z1 = tanh(Z0 @ W_dmid[0] + b_dmid[0])
  gemm_mfma<2><<<dim3(32,1,8), blk, 0, stream>>>(Z0, W_dmid, b_dmid, Z1, PART,
      2048, 2048, 2048, 2048, 0L, 0L, 0L, 0L, 8, 0);
  reduce_ep<<<dim3(1024), blk, 0, stream>>>(PART, b_dmid, Z1,
      8, 2048, 2048, 0L, 0L, 1, 128*2048, 1);
  // Z2 = tanh(Z1 @ W_dmid[1] + b_dmid[1])
  gemm_mfma<2><<<dim3(32,1,8), blk, 0, stream>>>(Z1, W_dmid + 4194304, b_dmid + 2048, Z2, PART,
      2048, 2048, 2048, 2048, 0L, 0L, 0L, 0L, 8, 0);
  reduce_ep<<<dim3(1024), blk, 0, stream>>>(PART, b_dmid + 2048, Z2,
      8, 2048, 2048, 0L, 0L, 1, 128*2048, 1);
  // Y = Z2 @ W_dout + b_dout -> d_out [1,128,1024]
  gemm_mfma<1><<<dim3(32,1,8), blk, 0, stream>>>(Z2, W_dout, b_dout, (float*)d_out, PART,
      1024, 2048, 2048, 1024, 0L, 0L, 0L, 0L, 8, 0);
  reduce_ep<<<dim3(512), blk, 0, stream>>>(PART, b_dout, (float*)d_out,
      8, 1024, 1024, 0L, 0L, 0, 128*1024, 1);
}